// Round 8
// baseline (25901.520 us; speedup 1.0000x reference)
//
#include <hip/hip_runtime.h>
#include <cstdint>
#include <cstddef>

#define NT 2048   // timesteps
#define NB 64     // batch
#define NH 256    // hidden
#define NG 768    // 3*NH
#define NL 3      // layers
#define CHUNK 128 // timesteps per chunk
#define NCH (NT / CHUNK)
#define NBB 16    // batches per scan block

typedef _Float16 h2 __attribute__((ext_vector_type(2)));
typedef _Float16 f16x8 __attribute__((ext_vector_type(8)));
typedef float f32x4 __attribute__((ext_vector_type(4)));
union HU { unsigned int u; h2 h; };

__device__ __forceinline__ float sigf(float x) {
    return 1.0f / (1.0f + __expf(-x));
}
__device__ __forceinline__ float tanhfast(float x) {
    float e = __expf(2.0f * x);
    return 1.0f - 2.0f / (e + 1.0f);
}
__device__ __forceinline__ f16x8 as_f16x8(uint4 u) {
    union { uint4 a; f16x8 b; } c; c.a = u; return c.b;
}
__device__ __forceinline__ uint4 pack8(const float* s) {
    HU u0, u1, u2, u3;
    u0.h = h2{(_Float16)s[0], (_Float16)s[1]};
    u1.h = h2{(_Float16)s[2], (_Float16)s[3]};
    u2.h = h2{(_Float16)s[4], (_Float16)s[5]};
    u3.h = h2{(_Float16)s[6], (_Float16)s[7]};
    return uint4{u0.u, u1.u, u2.u, u3.u};
}

// ---------------------------------------------------------------------------
// fp32 -> fp16 cast (vectorized, exact element count = n4*4)
// ---------------------------------------------------------------------------
__global__ void cast_f32_f16(const float* __restrict__ in, _Float16* __restrict__ outp,
                             int n4) {
    int i = blockIdx.x * 256 + threadIdx.x;
    if (i >= n4) return;
    float4 v = ((const float4*)in)[i];
    h2 a = {(_Float16)v.x, (_Float16)v.y};
    h2 b = {(_Float16)v.z, (_Float16)v.w};
    HU ua, ub; ua.h = a; ub.h = b;
    ((uint2*)outp)[i] = uint2{ua.u, ub.u};
}

// ---------------------------------------------------------------------------
// cb[l][g] = b_ih[l][g] + (g < 512 ? b_hh[l][g] : 0)   (fold r,z hidden bias
// into the gi GEMM bias; n-gate hidden bias stays separate — it sits inside
// r*(...) in the GRU cell).
// ---------------------------------------------------------------------------
__global__ void make_cbias(const float* __restrict__ bih, const float* __restrict__ bhh,
                           float* __restrict__ cb) {
    int i = blockIdx.x * 256 + threadIdx.x;
    if (i >= NL * NG) return;
    int g = i % NG;
    cb[i] = bih[i] + (g < 2 * NH ? bhh[i] : 0.0f);
}

// ---------------------------------------------------------------------------
// gi[M,768] = A[M,256] @ W[768,256](f16)^T + cbias(f32), via
// mfma_f32_16x16x32_f16. AF32=1: A is fp32 (layer 0, reads x directly);
// AF32=0: A is fp16 (scan output). Fragment convention verified R4-R7.
// ---------------------------------------------------------------------------
template<int AF32>
__global__ __launch_bounds__(256) void gemm_gi(const void* __restrict__ Av,
                                               const _Float16* __restrict__ W,
                                               const float* __restrict__ bias,
                                               float* __restrict__ C) {
    const int lane = threadIdx.x & 63;
    const int wv   = threadIdx.x >> 6;
    const int m0   = (blockIdx.y << 6) + (wv << 4);
    const int n0   = blockIdx.x << 6;
    const int r    = lane & 15;
    const int ko   = (lane >> 4) << 3;           // 0,8,16,24

    const _Float16* wrow = W + (size_t)(n0 + r) * NH + ko;

    f32x4 acc0 = {0,0,0,0}, acc1 = {0,0,0,0}, acc2 = {0,0,0,0}, acc3 = {0,0,0,0};
#pragma unroll
    for (int k0 = 0; k0 < 8; ++k0) {
        f16x8 af;
        if constexpr (AF32) {
            const float* ar = (const float*)Av + (size_t)(m0 + r) * NH + ko + k0 * 32;
            float4 u = *(const float4*)(ar);
            float4 v = *(const float4*)(ar + 4);
            af = f16x8{(_Float16)u.x, (_Float16)u.y, (_Float16)u.z, (_Float16)u.w,
                       (_Float16)v.x, (_Float16)v.y, (_Float16)v.z, (_Float16)v.w};
        } else {
            const _Float16* ar = (const _Float16*)Av + (size_t)(m0 + r) * NH + ko + k0 * 32;
            af = *(const f16x8*)(ar);
        }
        const f16x8 b0 = *(const f16x8*)(wrow + k0 * 32);
        const f16x8 b1 = *(const f16x8*)(wrow + 16 * NH + k0 * 32);
        const f16x8 b2 = *(const f16x8*)(wrow + 32 * NH + k0 * 32);
        const f16x8 b3 = *(const f16x8*)(wrow + 48 * NH + k0 * 32);
        acc0 = __builtin_amdgcn_mfma_f32_16x16x32_f16(af, b0, acc0, 0, 0, 0);
        acc1 = __builtin_amdgcn_mfma_f32_16x16x32_f16(af, b1, acc1, 0, 0, 0);
        acc2 = __builtin_amdgcn_mfma_f32_16x16x32_f16(af, b2, acc2, 0, 0, 0);
        acc3 = __builtin_amdgcn_mfma_f32_16x16x32_f16(af, b3, acc3, 0, 0, 0);
    }

    const int rowb = m0 + ((lane >> 4) << 2);
    const f32x4 av[4] = {acc0, acc1, acc2, acc3};
#pragma unroll
    for (int j = 0; j < 4; ++j) {
        const int col = n0 + (j << 4) + r;
        const float bb = bias[col];
#pragma unroll
        for (int q = 0; q < 4; ++q)
            C[(size_t)(rowb + q) * NG + col] = av[j][q] + bb;
    }
}

// ---------------------------------------------------------------------------
// MFMA GRU scan. 4 blocks x 512 threads (8 waves, 2/SIMD). Block bg owns
// batches bg*16..+15. Wave wv owns output cols wv*96..+95 (6 N-tiles),
// full K=256 (8 k-frags). Weights: 192 regs/wave of f16x8 B-frags, consumed
// only by MFMA (AGPR-resident is free). h: f16 in chunk-XOR-swizzled LDS
// (A-frags); f32 master copy in epilogue-thread registers. gh exchanged via
// [col][16+2] f32 LDS. 2 barriers/step.
// ---------------------------------------------------------------------------
__global__ __launch_bounds__(512, 2) void gru_scan(const float* __restrict__ gi,
                                                   const _Float16* __restrict__ w16,
                                                   const float* __restrict__ bhn,
                                                   float* __restrict__ hst,
                                                   _Float16* __restrict__ outf,
                                                   float* __restrict__ outl,
                                                   int steps) {
    const int tid  = threadIdx.x;
    const int lane = tid & 63;
    const int wv   = tid >> 6;        // 0..7
    const int l15  = lane & 15;
    const int l4   = lane >> 4;       // 0..3
    const int bg   = blockIdx.x;

    __shared__ uint4 h_lds[16 * 32];          // 8 KB, chunk-swizzled f16 h
    __shared__ float gh2[768 * 18];           // 55.3 KB, [col][row(16)+pad2]

    // ---- load weights: wave wv cols wv*96 + n*16 + l15, n = 0..5
    const int colb = wv * 96;
    f16x8 wb[6][8];
#pragma unroll
    for (int n = 0; n < 6; ++n) {
        const _Float16* wr = w16 + (size_t)(colb + n * 16 + l15) * NH + l4 * 8;
#pragma unroll
        for (int k0 = 0; k0 < 8; ++k0)
            wb[n][k0] = *(const f16x8*)(wr + k0 * 32);
    }

    // ---- h state: thread owns (batch r, cols j*8..j*8+7)
    const int r = tid & 15;
    const int j = tid >> 4;           // 0..31
    const int bglob = bg * NBB + r;
    float hp[8];
    {
        const float4* hs = (const float4*)(hst + (size_t)bglob * NH + j * 8);
        float4 v0 = hs[0], v1 = hs[1];
        hp[0] = v0.x; hp[1] = v0.y; hp[2] = v0.z; hp[3] = v0.w;
        hp[4] = v1.x; hp[5] = v1.y; hp[6] = v1.z; hp[7] = v1.w;
        h_lds[r * 32 + (j ^ r)] = pack8(hp);
    }
    const float* bnp = bhn + j * 8;
    __syncthreads();

    for (int st = 0; st < steps; ++st) {
        // ---- MFMA phase: A-frags from swizzled h_lds
        uint4 a[8];
#pragma unroll
        for (int k0 = 0; k0 < 8; ++k0)
            a[k0] = h_lds[l15 * 32 + (((k0 << 2) + l4) ^ l15)];

#pragma unroll
        for (int g = 0; g < 3; ++g) {
            f32x4 d0 = {0.f, 0.f, 0.f, 0.f}, d1 = {0.f, 0.f, 0.f, 0.f};
#pragma unroll
            for (int k0 = 0; k0 < 8; ++k0) {
                const f16x8 af = as_f16x8(a[k0]);
                d0 = __builtin_amdgcn_mfma_f32_16x16x32_f16(af, wb[g * 2 + 0][k0], d0, 0, 0, 0);
                d1 = __builtin_amdgcn_mfma_f32_16x16x32_f16(af, wb[g * 2 + 1][k0], d1, 0, 0, 0);
            }
            const int c0 = (colb + (g * 2 + 0) * 16 + l15) * 18 + (l4 << 2);
            const int c1 = (colb + (g * 2 + 1) * 16 + l15) * 18 + (l4 << 2);
            gh2[c0 + 0] = d0[0]; gh2[c0 + 1] = d0[1]; gh2[c0 + 2] = d0[2]; gh2[c0 + 3] = d0[3];
            gh2[c1 + 0] = d1[0]; gh2[c1 + 1] = d1[1]; gh2[c1 + 2] = d1[2]; gh2[c1 + 3] = d1[3];
        }

        // ---- gi + bhn loads issued pre-barrier (land under barrier + LDS reads)
        const float* gbase = gi + ((size_t)st * NB + bglob) * NG + j * 8;
        float4 gr0 = *(const float4*)(gbase);
        float4 gr1 = *(const float4*)(gbase + 4);
        float4 gz0 = *(const float4*)(gbase + 256);
        float4 gz1 = *(const float4*)(gbase + 260);
        float4 gn0 = *(const float4*)(gbase + 512);
        float4 gn1 = *(const float4*)(gbase + 516);
        float4 bn0 = *(const float4*)(bnp);
        float4 bn1 = *(const float4*)(bnp + 4);

        __syncthreads();                       // gh2 complete

        const float gr_[8] = {gr0.x, gr0.y, gr0.z, gr0.w, gr1.x, gr1.y, gr1.z, gr1.w};
        const float gz_[8] = {gz0.x, gz0.y, gz0.z, gz0.w, gz1.x, gz1.y, gz1.z, gz1.w};
        const float gn_[8] = {gn0.x, gn0.y, gn0.z, gn0.w, gn1.x, gn1.y, gn1.z, gn1.w};
        const float bn_[8] = {bn0.x, bn0.y, bn0.z, bn0.w, bn1.x, bn1.y, bn1.z, bn1.w};

#pragma unroll
        for (int cc = 0; cc < 8; ++cc) {
            const int col = j * 8 + cc;
            const float ghr = gh2[col * 18 + r];
            const float ghz = gh2[(col + 256) * 18 + r];
            const float ghn = gh2[(col + 512) * 18 + r];
            const float rr = sigf(gr_[cc] + ghr);
            const float zz = sigf(gz_[cc] + ghz);
            const float nn = tanhfast(gn_[cc] + rr * (ghn + bn_[cc]));
            hp[cc] = (1.0f - zz) * nn + zz * hp[cc];
        }

        const uint4 ph = pack8(hp);
        h_lds[r * 32 + (j ^ r)] = ph;
        if (outf) *(uint4*)(outf + ((size_t)st * NB + bglob) * NH + j * 8) = ph;
        __syncthreads();                       // h ready for next step
    }

    {
        float4 v0 = make_float4(hp[0], hp[1], hp[2], hp[3]);
        float4 v1 = make_float4(hp[4], hp[5], hp[6], hp[7]);
        float4* hd = (float4*)(hst + (size_t)bglob * NH + j * 8);
        hd[0] = v0; hd[1] = v1;
        if (outl) {
            float4* od = (float4*)(outl + (size_t)bglob * NH + j * 8);
            od[0] = v0; od[1] = v1;
        }
    }
}

// ---------------------------------------------------------------------------
extern "C" void kernel_launch(void* const* d_in, const int* in_sizes, int n_in,
                              void* d_out, int out_size, void* d_ws, size_t ws_size,
                              hipStream_t stream) {
    const float* x   = (const float*)d_in[0];   // [2048,64,256]
    const float* Wih = (const float*)d_in[1];   // [3,768,256]
    const float* Whh = (const float*)d_in[2];   // [3,768,256]
    const float* bih = (const float*)d_in[3];   // [3,768]
    const float* bhh = (const float*)d_in[4];   // [3,768]
    float* out = (float*)d_out;                 // [64,256]

    // workspace layout (16B-aligned) — total ~36 MB
    _Float16* wihh  = (_Float16*)d_ws;                         // 589,824 f16  1.18 MB
    _Float16* whh16 = wihh + (size_t)NL * NG * NH;             // 589,824 f16  1.18 MB
    float*    cb    = (float*)(whh16 + (size_t)NL * NG * NH);  // 2,304 f32
    float*    hst   = cb + NL * NG;                            // 49,152 f32   0.20 MB
    float*    gi    = hst + (size_t)NL * NB * NH;              // 6,291,456    25.2 MB
    _Float16* obA   = (_Float16*)(gi + (size_t)CHUNK * NB * NG); // 2,097,152  4.2 MB
    _Float16* obB   = obA + (size_t)CHUNK * NB * NH;           // 2,097,152    4.2 MB

    hipMemsetAsync(hst, 0, (size_t)NL * NB * NH * sizeof(float), stream);
    cast_f32_f16<<<576, 256, 0, stream>>>(Wih, wihh, NL * NG * NH / 4);
    cast_f32_f16<<<576, 256, 0, stream>>>(Whh, whh16, NL * NG * NH / 4);
    make_cbias<<<9, 256, 0, stream>>>(bih, bhh, cb);

    for (int c = 0; c < NCH; ++c) {
        for (int l = 0; l < NL; ++l) {
            const void* A = (l == 0) ? (const void*)(x + (size_t)c * CHUNK * NB * NH)
                                     : ((l == 1) ? (const void*)obA : (const void*)obB);
            if (l == 0)
                gemm_gi<1><<<dim3(12, CHUNK * NB / 64), 256, 0, stream>>>(
                    A, wihh + (size_t)l * NG * NH, cb + (size_t)l * NG, gi);
            else
                gemm_gi<0><<<dim3(12, CHUNK * NB / 64), 256, 0, stream>>>(
                    A, wihh + (size_t)l * NG * NH, cb + (size_t)l * NG, gi);
            _Float16* outf = (l == 0) ? obA : ((l == 1) ? obB : nullptr);
            float* outl = (l == 2 && c == NCH - 1) ? out : nullptr;
            gru_scan<<<4, 512, 0, stream>>>(
                gi, whh16 + (size_t)l * NG * NH, bhh + (size_t)l * NG + 2 * NH,
                hst + (size_t)l * NB * NH, outf, outl, CHUNK);
        }
    }
}

// Round 9
// 9212.395 us; speedup vs baseline: 2.8116x; 2.8116x over previous
//
#include <hip/hip_runtime.h>
#include <cstdint>
#include <cstddef>

#define NT 2048   // timesteps
#define NB 64     // batch
#define NH 256    // hidden
#define NG 768    // 3*NH
#define NL 3      // layers
#define CHUNK 128 // timesteps per chunk
#define NCH (NT / CHUNK)

typedef _Float16 h2 __attribute__((ext_vector_type(2)));
typedef _Float16 f16x8 __attribute__((ext_vector_type(8)));
typedef float f32x4 __attribute__((ext_vector_type(4)));
union HU { unsigned int u; h2 h; };

__device__ __forceinline__ float sigf(float x) {
    return 1.0f / (1.0f + __expf(-x));
}
__device__ __forceinline__ float tanhfast(float x) {
    float e = __expf(2.0f * x);
    return 1.0f - 2.0f / (e + 1.0f);
}

// 4x fdot2: acc += sum over 8 f16 pairs packed in wv (weights) * hv (h)
__device__ __forceinline__ float dot8(uint4 wv, uint4 hv, float acc) {
#if __has_builtin(__builtin_amdgcn_fdot2)
    HU a, b;
    a.u = wv.x; b.u = hv.x; acc = __builtin_amdgcn_fdot2(a.h, b.h, acc, false);
    a.u = wv.y; b.u = hv.y; acc = __builtin_amdgcn_fdot2(a.h, b.h, acc, false);
    a.u = wv.z; b.u = hv.z; acc = __builtin_amdgcn_fdot2(a.h, b.h, acc, false);
    a.u = wv.w; b.u = hv.w; acc = __builtin_amdgcn_fdot2(a.h, b.h, acc, false);
#else
    HU a, b;
    const unsigned int wu[4] = {wv.x, wv.y, wv.z, wv.w};
    const unsigned int hu[4] = {hv.x, hv.y, hv.z, hv.w};
#pragma unroll
    for (int i = 0; i < 4; ++i) {
        a.u = wu[i]; b.u = hu[i];
        acc = fmaf((float)a.h[0], (float)b.h[0], acc);
        acc = fmaf((float)a.h[1], (float)b.h[1], acc);
    }
#endif
    return acc;
}

// ---------------------------------------------------------------------------
// Repack W_hh (fp32 [3][768][256]) for the gate-split scan: thread t of the
// scan owns full row t (= gate*256+col) of W_hh[l]; chunk cc = k in
// [cc*8, cc*8+8), stored at wp[l][cc*768 + t] so weight loads coalesce.
// ---------------------------------------------------------------------------
__global__ void repack_whh(const float* __restrict__ whh, uint4* __restrict__ wp) {
    int idx = blockIdx.x * 256 + threadIdx.x;     // uint4 index, total 73728
    if (idx >= NL * 32 * 768) return;
    int t  = idx % 768;
    int cc = (idx / 768) % 32;
    int l  = idx / (768 * 32);
    const float* row = whh + ((size_t)l * NG + t) * NH + cc * 8;
    HU u0, u1, u2, u3;
    u0.h = h2{(_Float16)row[0], (_Float16)row[1]};
    u1.h = h2{(_Float16)row[2], (_Float16)row[3]};
    u2.h = h2{(_Float16)row[4], (_Float16)row[5]};
    u3.h = h2{(_Float16)row[6], (_Float16)row[7]};
    wp[idx] = uint4{u0.u, u1.u, u2.u, u3.u};
}

// ---------------------------------------------------------------------------
// fp32 -> fp16 cast (vectorized, exact element count = n4*4)
// ---------------------------------------------------------------------------
__global__ void cast_f32_f16(const float* __restrict__ in, _Float16* __restrict__ outp,
                             int n4) {
    int i = blockIdx.x * 256 + threadIdx.x;
    if (i >= n4) return;
    float4 v = ((const float4*)in)[i];
    h2 a = {(_Float16)v.x, (_Float16)v.y};
    h2 b = {(_Float16)v.z, (_Float16)v.w};
    HU ua, ub; ua.h = a; ub.h = b;
    ((uint2*)outp)[i] = uint2{ua.u, ub.u};
}

// ---------------------------------------------------------------------------
// cb[l][g] = b_ih[l][g] + (g < 512 ? b_hh[l][g] : 0)   (fold r,z hidden bias
// into the gi GEMM bias; n-gate hidden bias stays separate — it sits inside
// r*(...) in the GRU cell).
// ---------------------------------------------------------------------------
__global__ void make_cbias(const float* __restrict__ bih, const float* __restrict__ bhh,
                           float* __restrict__ cb) {
    int i = blockIdx.x * 256 + threadIdx.x;
    if (i >= NL * NG) return;
    int g = i % NG;
    cb[i] = bih[i] + (g < 2 * NH ? bhh[i] : 0.0f);
}

// ---------------------------------------------------------------------------
// gi[M,768] = A[M,256] @ W[768,256](f16)^T + cbias(f32), via
// mfma_f32_16x16x32_f16. AF32=1: A is fp32 (layer 0, reads x directly);
// AF32=0: A is fp16 (scan output). Fragment convention verified R4-R8.
// ---------------------------------------------------------------------------
template<int AF32>
__global__ __launch_bounds__(256) void gemm_gi(const void* __restrict__ Av,
                                               const _Float16* __restrict__ W,
                                               const float* __restrict__ bias,
                                               float* __restrict__ C) {
    const int lane = threadIdx.x & 63;
    const int wv   = threadIdx.x >> 6;
    const int m0   = (blockIdx.y << 6) + (wv << 4);
    const int n0   = blockIdx.x << 6;
    const int r    = lane & 15;
    const int ko   = (lane >> 4) << 3;           // 0,8,16,24

    const _Float16* wrow = W + (size_t)(n0 + r) * NH + ko;

    f32x4 acc0 = {0,0,0,0}, acc1 = {0,0,0,0}, acc2 = {0,0,0,0}, acc3 = {0,0,0,0};
#pragma unroll
    for (int k0 = 0; k0 < 8; ++k0) {
        f16x8 af;
        if constexpr (AF32) {
            const float* ar = (const float*)Av + (size_t)(m0 + r) * NH + ko + k0 * 32;
            float4 u = *(const float4*)(ar);
            float4 v = *(const float4*)(ar + 4);
            af = f16x8{(_Float16)u.x, (_Float16)u.y, (_Float16)u.z, (_Float16)u.w,
                       (_Float16)v.x, (_Float16)v.y, (_Float16)v.z, (_Float16)v.w};
        } else {
            const _Float16* ar = (const _Float16*)Av + (size_t)(m0 + r) * NH + ko + k0 * 32;
            af = *(const f16x8*)(ar);
        }
        const f16x8 b0 = *(const f16x8*)(wrow + k0 * 32);
        const f16x8 b1 = *(const f16x8*)(wrow + 16 * NH + k0 * 32);
        const f16x8 b2 = *(const f16x8*)(wrow + 32 * NH + k0 * 32);
        const f16x8 b3 = *(const f16x8*)(wrow + 48 * NH + k0 * 32);
        acc0 = __builtin_amdgcn_mfma_f32_16x16x32_f16(af, b0, acc0, 0, 0, 0);
        acc1 = __builtin_amdgcn_mfma_f32_16x16x32_f16(af, b1, acc1, 0, 0, 0);
        acc2 = __builtin_amdgcn_mfma_f32_16x16x32_f16(af, b2, acc2, 0, 0, 0);
        acc3 = __builtin_amdgcn_mfma_f32_16x16x32_f16(af, b3, acc3, 0, 0, 0);
    }

    const int rowb = m0 + ((lane >> 4) << 2);
    const f32x4 av[4] = {acc0, acc1, acc2, acc3};
#pragma unroll
    for (int j = 0; j < 4; ++j) {
        const int col = n0 + (j << 4) + r;
        const float bb = bias[col];
#pragma unroll
        for (int q = 0; q < 4; ++q)
            C[(size_t)(rowb + q) * NG + col] = av[j][q] + bb;
    }
}

// ---------------------------------------------------------------------------
// Gate-split register-resident GRU scan. 64 blocks (one per batch) x 768
// threads (12 waves, 3/SIMD -> 170-reg budget). Thread t owns W_hh row t
// (gate t>>8, col t&255): 32 uint4 = 128 VGPRs; working set ~20 regs ->
// real headroom, no spill pressure. Full-K dot per thread (no reduce).
// h: f16 in 512B LDS, read as uniform-address b128 broadcasts (free).
// Per-step exchange: aL[3][260] padded f32 (conflict-free). 2 barriers/step.
// Epilogue on threads t<256 (waves 0-3, wave-uniform branch).
// ---------------------------------------------------------------------------
__global__ __launch_bounds__(768, 3) void gru_scan(const float* __restrict__ gi,
                                                   const uint4* __restrict__ wp,
                                                   const float* __restrict__ bhn,
                                                   float* __restrict__ hst,
                                                   _Float16* __restrict__ outf,
                                                   float* __restrict__ outl,
                                                   int steps) {
    const int b = blockIdx.x;
    const int t = threadIdx.x;        // gate g = t>>8, col c = t&255
    const int c = t & 255;
    __shared__ __align__(16) _Float16 hsm[NH];    // 512 B
    __shared__ float aL[3 * 260];                 // 3.1 KB, padded stride

    // 32 weight chunks = this thread's full W_hh row (coalesced loads)
    uint4 w[32];
#pragma unroll
    for (int cc = 0; cc < 32; ++cc) w[cc] = wp[cc * 768 + t];

    const bool ep = (t < NH);         // epilogue ownership: waves 0-3
    float h = 0.0f, bn = 0.0f;
    if (ep) {
        h  = hst[b * NH + c];
        bn = bhn[c];
        hsm[c] = (_Float16)h;
    }
    __syncthreads();

    float g_r = 0.f, g_z = 0.f, g_n = 0.f;
    if (ep) {
        const float* g0 = gi + (size_t)b * NG;
        g_r = g0[c]; g_z = g0[NH + c]; g_n = g0[2 * NH + c];
    }

    for (int st = 0; st < steps; ++st) {
        // prefetch next step's gi (lands under the dot phase)
        float p_r = 0.f, p_z = 0.f, p_n = 0.f;
        if (ep) {
            const int stq = (st + 1 < steps) ? (st + 1) : st;
            const float* gq = gi + ((size_t)stq * NB + b) * NG;
            p_r = gq[c]; p_z = gq[NH + c]; p_n = gq[2 * NH + c];
        }

        const uint4* hv = (const uint4*)hsm;     // uniform-addr broadcasts
        float acc = 0.0f;
#pragma unroll
        for (int cc = 0; cc < 32; ++cc) acc = dot8(w[cc], hv[cc], acc);
        aL[(t >> 8) * 260 + c] = acc;
        __syncthreads();                          // aL complete

        if (ep) {
            const float ar = aL[c];
            const float az = aL[260 + c];
            const float an = aL[520 + c];
            const float rr = sigf(g_r + ar);
            const float zz = sigf(g_z + az);
            const float nn = tanhfast(g_n + rr * (an + bn));
            h = (1.0f - zz) * nn + zz * h;
            hsm[c] = (_Float16)h;
            if (outf) outf[((size_t)st * NB + b) * NH + c] = (_Float16)h;
        }
        g_r = p_r; g_z = p_z; g_n = p_n;
        __syncthreads();                          // new h visible
    }

    if (ep) {
        hst[b * NH + c] = h;
        if (outl) outl[b * NH + c] = h;
    }
}

// ---------------------------------------------------------------------------
extern "C" void kernel_launch(void* const* d_in, const int* in_sizes, int n_in,
                              void* d_out, int out_size, void* d_ws, size_t ws_size,
                              hipStream_t stream) {
    const float* x   = (const float*)d_in[0];   // [2048,64,256]
    const float* Wih = (const float*)d_in[1];   // [3,768,256]
    const float* Whh = (const float*)d_in[2];   // [3,768,256]
    const float* bih = (const float*)d_in[3];   // [3,768]
    const float* bhh = (const float*)d_in[4];   // [3,768]
    float* out = (float*)d_out;                 // [64,256]

    // workspace layout (16B-aligned) — total ~36 MB
    uint4*    wpack = (uint4*)d_ws;                            // 73,728 u4    1.18 MB
    _Float16* wihh  = (_Float16*)(wpack + (size_t)NL * 32 * 768); // 589,824   1.18 MB
    float*    cb    = (float*)(wihh + (size_t)NL * NG * NH);   // 2,304 f32
    float*    hst   = cb + NL * NG;                            // 49,152 f32   0.20 MB
    float*    gi    = hst + (size_t)NL * NB * NH;              // 6,291,456    25.2 MB
    _Float16* obA   = (_Float16*)(gi + (size_t)CHUNK * NB * NG); // 2,097,152  4.2 MB
    _Float16* obB   = obA + (size_t)CHUNK * NB * NH;           // 2,097,152    4.2 MB

    hipMemsetAsync(hst, 0, (size_t)NL * NB * NH * sizeof(float), stream);
    repack_whh<<<288, 256, 0, stream>>>(Whh, wpack);
    cast_f32_f16<<<576, 256, 0, stream>>>(Wih, wihh, NL * NG * NH / 4);
    make_cbias<<<9, 256, 0, stream>>>(bih, bhh, cb);

    for (int c = 0; c < NCH; ++c) {
        for (int l = 0; l < NL; ++l) {
            const void* A = (l == 0) ? (const void*)(x + (size_t)c * CHUNK * NB * NH)
                                     : ((l == 1) ? (const void*)obA : (const void*)obB);
            if (l == 0)
                gemm_gi<1><<<dim3(12, CHUNK * NB / 64), 256, 0, stream>>>(
                    A, wihh + (size_t)l * NG * NH, cb + (size_t)l * NG, gi);
            else
                gemm_gi<0><<<dim3(12, CHUNK * NB / 64), 256, 0, stream>>>(
                    A, wihh + (size_t)l * NG * NH, cb + (size_t)l * NG, gi);
            _Float16* outf = (l == 0) ? obA : ((l == 1) ? obB : nullptr);
            float* outl = (l == 2 && c == NCH - 1) ? out : nullptr;
            gru_scan<<<NB, 768, 0, stream>>>(
                gi, wpack + (size_t)l * 32 * 768, bhh + (size_t)l * NG + 2 * NH,
                hst + (size_t)l * NB * NH, outf, outl, CHUNK);
        }
    }
}